// Round 12
// baseline (204.636 us; speedup 1.0000x reference)
//
#include <hip/hip_runtime.h>

typedef unsigned short u16;
typedef __attribute__((ext_vector_type(8))) short bf16x8;   // MFMA A/B frag (8 bf16)
typedef __attribute__((ext_vector_type(4))) short s16x4;    // 4 bf16 (K=16 A/B frag)
typedef __attribute__((ext_vector_type(2))) int i32x2;      // same 8 bytes as s16x4
typedef __attribute__((ext_vector_type(4))) float f32x4;    // MFMA C/D frag

#define MFMA16(a, b, c) __builtin_amdgcn_mfma_f32_16x16x32_bf16((a), (b), (c), 0, 0, 0)

// K=16 bf16 MFMA. Prefer the builtin (compiler-managed MFMA hazards/scheduling).
__device__ __forceinline__ void mfma161616(i32x2 a, i32x2 b, f32x4& c) {
#if __has_builtin(__builtin_amdgcn_mfma_f32_16x16x16bf16_1k)
    union { i32x2 i; s16x4 s; } ua{a}, ub{b};
    c = __builtin_amdgcn_mfma_f32_16x16x16bf16_1k(ua.s, ub.s, c, 0, 0, 0);
#else
    asm("v_mfma_f32_16x16x16_bf16 %0, %1, %2, %0" : "+v"(c) : "v"(a), "v"(b));
#endif
}

// async global->LDS, 16B per lane; LDS dest = wave-uniform base + lane*16
__device__ __forceinline__ void gll16(const void* g, void* l) {
    __builtin_amdgcn_global_load_lds(
        (const __attribute__((address_space(1))) unsigned int*)g,
        (__attribute__((address_space(3))) unsigned int*)l, 16, 0, 0);
}

__device__ __forceinline__ u16 f2b(float f) {   // f32 -> bf16 RNE (scalar)
    unsigned int u = __float_as_uint(f);
    u += 0x7fffu + ((u >> 16) & 1u);
    return (u16)(u >> 16);
}

// packed bf16x2 via HW converter (RNE)
__device__ __forceinline__ unsigned int pkcvt(float a, float b) {
    unsigned int r;
    asm("v_cvt_pk_bf16_f32 %0, %1, %2" : "=v"(r) : "v"(a), "v"(b));
    return r;
}

// ---------------------------------------------------------------- one cast kernel
__global__ __launch_bounds__(256) void cast_all(const float* __restrict__ x,
                                                const float* __restrict__ w0,
                                                const float* __restrict__ w1,
                                                const float* __restrict__ w2,
                                                const float* __restrict__ w3,
                                                u16* __restrict__ xb,
                                                u16* __restrict__ wb) {
    const int bid = blockIdx.x;
    const float* s; u16* d; int off;
    if (bid < 2048) { s = x; d = xb; off = bid; }
    else {
        const int wi = (bid - 2048) >> 9;
        s = (wi == 0) ? w0 : (wi == 1) ? w1 : (wi == 2) ? w2 : w3;
        d = wb + (size_t)wi * 1048576;
        off = (bid - 2048) & 511;
    }
    const int i = (off * 256 + threadIdx.x) * 8;
    float4 a = *(const float4*)(s + i);
    float4 b = *(const float4*)(s + i + 4);
    *(uint4*)(d + i) = make_uint4(pkcvt(a.x, a.y), pkcvt(a.z, a.w),
                                  pkcvt(b.x, b.y), pkcvt(b.z, b.w));
}

// ---------------------------------------------------------------- GEMM, dbuf K-loop
// R4-proven structure. QKV: 128x128, 768 blocks (3/CU). o-proj: 128x64,
// 512 blocks (2/CU), SLOTS=2.
template <int BM, int BN, int MODE, int SLOTS>
__global__ __launch_bounds__(256) void gemm_bt(const u16* __restrict__ A,
                                               const u16* __restrict__ W,
                                               void* __restrict__ Yv,
                                               u16* __restrict__ vT,
                                               int K, int ldY) {
    constexpr int MI = BM / 32, NJ = BN / 32;
    constexpr int ACH = BM / 16;
    constexpr int NPW = (BM + BN) / 64;
    __shared__ u16 As[2][SLOTS][BM * 32];
    __shared__ u16 Bs[2][SLOTS][BN * 32];
    const int t = threadIdx.x, w = t >> 6, lane = t & 63;
    const int quad = lane >> 4, m16 = lane & 15;
    const int wr = (w >> 1) * (BM / 2), wc = (w & 1) * (BN / 2);
    const int row0 = blockIdx.x * BM, col0 = blockIdx.y * BN;
    const int srow = lane >> 2, scol = (lane & 3) * 8;

    auto stage = [&](int buf, int slot, int k0) {
#pragma unroll
        for (int cc = 0; cc < NPW; ++cc) {
            const int c = w * NPW + cc;
            if (c < ACH)
                gll16(A + (size_t)(row0 + c * 16 + srow) * K + k0 + scol,
                      &As[buf][slot][c * 512]);
            else
                gll16(W + (size_t)(col0 + (c - ACH) * 16 + srow) * K + k0 + scol,
                      &Bs[buf][slot][(c - ACH) * 512]);
        }
    };

    f32x4 acc[MI][NJ];
#pragma unroll
    for (int i = 0; i < MI; ++i)
#pragma unroll
        for (int j = 0; j < NJ; ++j) acc[i][j] = (f32x4){0.f, 0.f, 0.f, 0.f};

    auto compute_tile = [&](int buf, int slot) {
        bf16x8 af[MI], bf[NJ];
#pragma unroll
        for (int i = 0; i < MI; ++i)
            af[i] = *(const bf16x8*)&As[buf][slot][(wr + i * 16 + m16) * 32 + quad * 8];
#pragma unroll
        for (int j = 0; j < NJ; ++j)
            bf[j] = *(const bf16x8*)&Bs[buf][slot][(wc + j * 16 + m16) * 32 + quad * 8];
#pragma unroll
        for (int i = 0; i < MI; ++i)
#pragma unroll
            for (int j = 0; j < NJ; ++j) acc[i][j] = MFMA16(af[i], bf[j], acc[i][j]);
    };

#pragma unroll
    for (int s = 0; s < SLOTS; ++s) stage(0, s, s * 32);
    const int ngroups = K / (32 * SLOTS);
    for (int g = 0; g < ngroups; ++g) {
        const int buf = g & 1;
        __syncthreads();
        const int kn = (g + 1) * SLOTS * 32;
        if (kn < K) {
#pragma unroll
            for (int s = 0; s < SLOTS; ++s) stage(buf ^ 1, s, kn + s * 32);
        }
#pragma unroll
        for (int s = 0; s < SLOTS; ++s) compute_tile(buf, s);
    }
    if constexpr (MODE == 0) {
#pragma unroll
        for (int i = 0; i < MI; ++i)
#pragma unroll
            for (int j = 0; j < NJ; ++j)
#pragma unroll
                for (int r = 0; r < 4; ++r)
                    ((float*)Yv)[(size_t)(row0 + wr + i * 16 + quad * 4 + r) * ldY +
                                 col0 + wc + j * 16 + m16] = acc[i][j][r];
    } else {
        if (col0 < 2048) {
            u16* qk = (u16*)Yv;
#pragma unroll
            for (int i = 0; i < MI; ++i)
#pragma unroll
                for (int j = 0; j < NJ; ++j)
#pragma unroll
                    for (int r = 0; r < 4; ++r)
                        qk[(size_t)(row0 + wr + i * 16 + quad * 4 + r) * 2048 +
                           col0 + wc + j * 16 + m16] = f2b(acc[i][j][r]);
        } else {
#pragma unroll
            for (int i = 0; i < MI; ++i) {
                const int rbase = row0 + wr + i * 16;
                const int bb = rbase >> 10;
                const int tok0 = (rbase & 1023) + quad * 4;
#pragma unroll
                for (int j = 0; j < NJ; ++j) {
                    const int vTrow = bb * 1024 + (col0 + wc + j * 16 + m16 - 2048);
                    *(uint2*)(vT + (size_t)vTrow * 1024 + tok0) =
                        make_uint2(pkcvt(acc[i][j][0], acc[i][j][1]),
                                   pkcvt(acc[i][j][2], acc[i][j][3]));
                }
            }
        }
    }
}

// ---------------------------------------------------------------- based attention
// R12: occupancy restructure. R11 PMC: MfmaUtil 9.6%, VALU 20%, HBM 15%, Occ 18%
// — latency-bound, nothing saturated. R5's occupancy null explained: grid was
// 512 = 2 blocks/CU regardless of LDS. Fix BOTH: one 64-row q-tile per block
// (grid 16x16x4 = 1024 = 4 resident/CU), single unit per kt step (no pairing),
// LDS 32KB (5-block capacity). Zero-LDS-S PV kept from R9: QK^T S-frag is
// directly the K=16 MFMA B-operand; den = scalar sum + 2 shfl_xor.
__global__ __launch_bounds__(256) void based_attn(const u16* __restrict__ qkm,
                                                  const u16* __restrict__ vT,
                                                  u16* __restrict__ o) {
    __shared__ u16 ks[2][2][64][32];   // [buf][dblk][key][32 dims]   16KB
    __shared__ u16 vs[2][2][64][32];   // [buf][kblk][vdim][32 keys]  16KB

    const int t = threadIdx.x, w = t >> 6, lane = t & 63;
    const int quad = lane >> 4, m16 = lane & 15;
    const int tq = blockIdx.x, h = blockIdx.y, b = blockIdx.z;   // q-tile, head, batch
    const int srow = lane >> 2, s8 = (lane & 3) * 8;
    const int qrow = w * 16 + m16;       // lane's q-row within the tile

    const size_t qbase = (size_t)b * 1024 * 2048 + h * 64;
    const size_t kbase = qbase + 1024;
    const size_t vbase = ((size_t)b * 1024 + h * 64) * 1024;

    bf16x8 qf[2];
#pragma unroll
    for (int kd = 0; kd < 2; ++kd)
        qf[kd] = *(const bf16x8*)(qkm + qbase +
                  (size_t)(tq * 64 + qrow) * 2048 + kd * 32 + quad * 8);

    auto stage_tile = [&](int kt, int buf) {
#pragma unroll
        for (int cc = 0; cc < 2; ++cc) {
            const int c = w * 2 + cc;
            const int blk = c >> 2, rc = c & 3;
            gll16(qkm + kbase + (size_t)(kt * 64 + rc * 16 + srow) * 2048 + blk * 32 + s8,
                  &ks[buf][blk][rc * 16][0]);
            gll16(vT + vbase + (size_t)(rc * 16 + srow) * 1024 + kt * 64 + blk * 32 + s8,
                  &vs[buf][blk][rc * 16][0]);
        }
    };

    f32x4 num[4];                        // num^T: row=vd(quad*4+r in j-tile), col=q
    float dens = 0.f;                    // per-lane partial of den[q=m16]
#pragma unroll
    for (int j = 0; j < 4; ++j) num[j] = (f32x4){0.f, 0.f, 0.f, 0.f};

    auto compute = [&](int buf, int kt) {
        // ---- Phase 1: S^T = K * Q^T
        f32x4 s[4];
#pragma unroll
        for (int jk = 0; jk < 4; ++jk) s[jk] = (f32x4){0.f, 0.f, 0.f, 0.f};
        __builtin_amdgcn_s_setprio(1);
#pragma unroll
        for (int kd = 0; kd < 2; ++kd)
#pragma unroll
            for (int jk = 0; jk < 4; ++jk) {
                bf16x8 af = *(const bf16x8*)&ks[buf][kd][jk * 16 + m16][quad * 8];
                s[jk] = MFMA16(af, qf[kd], s[jk]);
            }
        __builtin_amdgcn_s_setprio(0);
        // ---- transform + mask + pack (register-resident S)
        i32x2 sb[4];
#pragma unroll
        for (int jk = 0; jk < 4; ++jk) {
            const int kl = jk * 16 + quad * 4;
            float sc[4];
#pragma unroll
            for (int r = 0; r < 4; ++r) {
                const float u = fmaf(s[jk][r], 0.125f, 1.0f);
                sc[r] = fmaf(u * 0.5f, u, 0.5f);
            }
            if (kt == tq) {
#pragma unroll
                for (int r = 0; r < 4; ++r)
                    if (kl + r > qrow) sc[r] = 0.f;
            }
            dens += sc[0] + sc[1] + sc[2] + sc[3];
            sb[jk][0] = (int)pkcvt(sc[0], sc[1]);
            sb[jk][1] = (int)pkcvt(sc[2], sc[3]);
        }
        // ---- Phase 2: num^T += V^T * S (K=16 MFMA; S straight from regs)
        __builtin_amdgcn_s_setprio(1);
#pragma unroll
        for (int jk = 0; jk < 4; ++jk) {
            const int kb = jk >> 1, ko = (jk & 1) * 16 + quad * 4;
#pragma unroll
            for (int j = 0; j < 4; ++j) {
                i32x2 va = *(const i32x2*)&vs[buf][kb][j * 16 + m16][ko];
                mfma161616(va, sb[jk], num[j]);
            }
        }
        __builtin_amdgcn_s_setprio(0);
    };

    stage_tile(0, 0);
    for (int kt = 0; kt <= tq; ++kt) {
        const int buf = kt & 1;
        __syncthreads();                  // tile kt landed; buf^1 free
        if (kt < tq) stage_tile(kt + 1, buf ^ 1);
        compute(buf, kt);
    }

    // ---- den reduce across quads (4 lanes share q=m16), then epilogue
    dens += __shfl_xor(dens, 16); dens += __shfl_xor(dens, 32);
    const float inv = 1.0f / dens;
    const size_t tok = (size_t)(b * 1024 + tq * 64 + qrow);
#pragma unroll
    for (int j = 0; j < 4; ++j)
        *(uint2*)(o + tok * 1024 + h * 64 + j * 16 + quad * 4) =
            make_uint2(pkcvt(num[j][0] * inv, num[j][1] * inv),
                       pkcvt(num[j][2] * inv, num[j][3] * inv));
}

// ---------------------------------------------------------------- launch
extern "C" void kernel_launch(void* const* d_in, const int* in_sizes, int n_in,
                              void* d_out, int out_size, void* d_ws, size_t ws_size,
                              hipStream_t stream) {
    const float* x  = (const float*)d_in[0];
    const float* Wq = (const float*)d_in[1];
    const float* Wk = (const float*)d_in[2];
    const float* Wv = (const float*)d_in[3];
    const float* Wo = (const float*)d_in[4];
    float* out = (float*)d_out;

    const size_t MEL = 4096ull * 1024ull;        // 4M elements
    u16* xb   = (u16*)d_ws;                      // 4096 x 1024
    u16* Wqkv = xb + MEL;                        // 3072 x 1024 (Wq|Wk|Wv rows)
    u16* Wob  = Wqkv + 3ull * 1024 * 1024;       // 1024 x 1024
    u16* qk   = Wob + 1024ull * 1024;            // 4096 x 2048 (q|k)
    u16* vT   = qk + 2ull * MEL;                 // [b*1024+h*64+vd][1024 tokens]
    u16* o    = vT + MEL;                        // 4096 x 1024

    cast_all<<<4096, 256, 0, stream>>>(x, Wq, Wk, Wv, Wo, xb, Wqkv);

    dim3 gq(32, 24);   // 128^2, 768 blocks = 3/CU (R4 proven)
    gemm_bt<128, 128, 1, 1><<<gq, 256, 0, stream>>>(xb, Wqkv, qk, vT, 1024, 2048);

    // R12: one q-tile per block, 1024 blocks = 4/CU, 32KB LDS — occupancy play
    dim3 ga(16, 16, 4); // q-tile x heads x batch
    based_attn<<<ga, 256, 0, stream>>>(qk, vT, o);

    dim3 go(32, 16);   // o-proj 128x64, 512 blocks = 2/CU (R4 proven)
    gemm_bt<128, 64, 0, 2><<<go, 256, 0, stream>>>(o, Wob, (void*)out, nullptr, 1024, 1024);
}

// Round 13
// 158.739 us; speedup vs baseline: 1.2891x; 1.2891x over previous
//
#include <hip/hip_runtime.h>

typedef unsigned short u16;
typedef __attribute__((ext_vector_type(8))) short bf16x8;   // MFMA A/B frag (8 bf16)
typedef __attribute__((ext_vector_type(4))) float f32x4;    // MFMA C/D frag

#define MFMA16(a, b, c) __builtin_amdgcn_mfma_f32_16x16x32_bf16((a), (b), (c), 0, 0, 0)

// async global->LDS, 16B per lane; LDS dest = wave-uniform base + lane*16
__device__ __forceinline__ void gll16(const void* g, void* l) {
    __builtin_amdgcn_global_load_lds(
        (const __attribute__((address_space(1))) unsigned int*)g,
        (__attribute__((address_space(3))) unsigned int*)l, 16, 0, 0);
}

__device__ __forceinline__ u16 f2b(float f) {   // f32 -> bf16 RNE (scalar)
    unsigned int u = __float_as_uint(f);
    u += 0x7fffu + ((u >> 16) & 1u);
    return (u16)(u >> 16);
}

// packed bf16x2 via HW converter (RNE)
__device__ __forceinline__ unsigned int pkcvt(float a, float b) {
    unsigned int r;
    asm("v_cvt_pk_bf16_f32 %0, %1, %2" : "=v"(r) : "v"(a), "v"(b));
    return r;
}

// ---------------------------------------------------------------- one cast kernel
__global__ __launch_bounds__(256) void cast_all(const float* __restrict__ x,
                                                const float* __restrict__ w0,
                                                const float* __restrict__ w1,
                                                const float* __restrict__ w2,
                                                const float* __restrict__ w3,
                                                u16* __restrict__ xb,
                                                u16* __restrict__ wb) {
    const int bid = blockIdx.x;
    const float* s; u16* d; int off;
    if (bid < 2048) { s = x; d = xb; off = bid; }
    else {
        const int wi = (bid - 2048) >> 9;
        s = (wi == 0) ? w0 : (wi == 1) ? w1 : (wi == 2) ? w2 : w3;
        d = wb + (size_t)wi * 1048576;
        off = (bid - 2048) & 511;
    }
    const int i = (off * 256 + threadIdx.x) * 8;
    float4 a = *(const float4*)(s + i);
    float4 b = *(const float4*)(s + i + 4);
    *(uint4*)(d + i) = make_uint4(pkcvt(a.x, a.y), pkcvt(a.z, a.w),
                                  pkcvt(b.x, b.y), pkcvt(b.z, b.w));
}

// ---------------------------------------------------------------- GEMM, dbuf K-loop
// R4-proven structure, frozen. QKV: 128x128, 768 blocks (3/CU). o-proj: 128x64,
// 512 blocks (2/CU), SLOTS=2. (T2 swizzle NOT applied here: documented null on
// 2-phase GEMM structures — conflicts hidden behind stage+barrier drain.)
template <int BM, int BN, int MODE, int SLOTS>
__global__ __launch_bounds__(256) void gemm_bt(const u16* __restrict__ A,
                                               const u16* __restrict__ W,
                                               void* __restrict__ Yv,
                                               u16* __restrict__ vT,
                                               int K, int ldY) {
    constexpr int MI = BM / 32, NJ = BN / 32;
    constexpr int ACH = BM / 16;
    constexpr int NPW = (BM + BN) / 64;
    __shared__ u16 As[2][SLOTS][BM * 32];
    __shared__ u16 Bs[2][SLOTS][BN * 32];
    const int t = threadIdx.x, w = t >> 6, lane = t & 63;
    const int quad = lane >> 4, m16 = lane & 15;
    const int wr = (w >> 1) * (BM / 2), wc = (w & 1) * (BN / 2);
    const int row0 = blockIdx.x * BM, col0 = blockIdx.y * BN;
    const int srow = lane >> 2, scol = (lane & 3) * 8;

    auto stage = [&](int buf, int slot, int k0) {
#pragma unroll
        for (int cc = 0; cc < NPW; ++cc) {
            const int c = w * NPW + cc;
            if (c < ACH)
                gll16(A + (size_t)(row0 + c * 16 + srow) * K + k0 + scol,
                      &As[buf][slot][c * 512]);
            else
                gll16(W + (size_t)(col0 + (c - ACH) * 16 + srow) * K + k0 + scol,
                      &Bs[buf][slot][(c - ACH) * 512]);
        }
    };

    f32x4 acc[MI][NJ];
#pragma unroll
    for (int i = 0; i < MI; ++i)
#pragma unroll
        for (int j = 0; j < NJ; ++j) acc[i][j] = (f32x4){0.f, 0.f, 0.f, 0.f};

    auto compute_tile = [&](int buf, int slot) {
        bf16x8 af[MI], bf[NJ];
#pragma unroll
        for (int i = 0; i < MI; ++i)
            af[i] = *(const bf16x8*)&As[buf][slot][(wr + i * 16 + m16) * 32 + quad * 8];
#pragma unroll
        for (int j = 0; j < NJ; ++j)
            bf[j] = *(const bf16x8*)&Bs[buf][slot][(wc + j * 16 + m16) * 32 + quad * 8];
#pragma unroll
        for (int i = 0; i < MI; ++i)
#pragma unroll
            for (int j = 0; j < NJ; ++j) acc[i][j] = MFMA16(af[i], bf[j], acc[i][j]);
    };

#pragma unroll
    for (int s = 0; s < SLOTS; ++s) stage(0, s, s * 32);
    const int ngroups = K / (32 * SLOTS);
    for (int g = 0; g < ngroups; ++g) {
        const int buf = g & 1;
        __syncthreads();
        const int kn = (g + 1) * SLOTS * 32;
        if (kn < K) {
#pragma unroll
            for (int s = 0; s < SLOTS; ++s) stage(buf ^ 1, s, kn + s * 32);
        }
#pragma unroll
        for (int s = 0; s < SLOTS; ++s) compute_tile(buf, s);
    }
    if constexpr (MODE == 0) {
#pragma unroll
        for (int i = 0; i < MI; ++i)
#pragma unroll
            for (int j = 0; j < NJ; ++j)
#pragma unroll
                for (int r = 0; r < 4; ++r)
                    ((float*)Yv)[(size_t)(row0 + wr + i * 16 + quad * 4 + r) * ldY +
                                 col0 + wc + j * 16 + m16] = acc[i][j][r];
    } else {
        if (col0 < 2048) {
            u16* qk = (u16*)Yv;
#pragma unroll
            for (int i = 0; i < MI; ++i)
#pragma unroll
                for (int j = 0; j < NJ; ++j)
#pragma unroll
                    for (int r = 0; r < 4; ++r)
                        qk[(size_t)(row0 + wr + i * 16 + quad * 4 + r) * 2048 +
                           col0 + wc + j * 16 + m16] = f2b(acc[i][j][r]);
        } else {
#pragma unroll
            for (int i = 0; i < MI; ++i) {
                const int rbase = row0 + wr + i * 16;
                const int bb = rbase >> 10;
                const int tok0 = (rbase & 1023) + quad * 4;
#pragma unroll
                for (int j = 0; j < NJ; ++j) {
                    const int vTrow = bb * 1024 + (col0 + wc + j * 16 + m16 - 2048);
                    *(uint2*)(vT + (size_t)vTrow * 1024 + tok0) =
                        make_uint2(pkcvt(acc[i][j][0], acc[i][j][1]),
                                   pkcvt(acc[i][j][2], acc[i][j][3]));
                }
            }
        }
    }
}

// ---------------------------------------------------------------- based attention
// R13 = R4's measured-best structure + LDS bank-conflict swizzle (the ONE change).
// Analysis: every LDS access here was 8-way conflicted (b128 frag reads at 64B
// row stride: even-m16 lanes of a quad share 4 banks at distinct addrs; Ss
// write->read round-trip likewise, ON the same-wave lgkmcnt serial chain).
// Fix: XOR the 16B-slot index with sx=(row>>1)&3 -> 2-way (free, m136).
//  - ks/vs (gll16-staged, rule #21): LDS dest stays linear; SOURCE slot
//    pre-swizzled ((l&3)^((l>>3)&3)); reads use (quad^sx).
//  - Ss (plain ds_write/read, lane owns its row): direct XOR both sides.
// R12 lesson: pairing (2 units/wave ILP) is load-bearing — kept. Grid 512=2/CU.
__global__ __launch_bounds__(256) void based_attn(const u16* __restrict__ qkm,
                                                  const u16* __restrict__ vT,
                                                  u16* __restrict__ o) {
    __shared__ u16 ks[2][2][2][64][32];  // [buf][slot][dblk][key][32]
    __shared__ u16 vs[2][2][2][64][32];  // [buf][slot][kb][vdim][32 keys]
    __shared__ u16 SsA[2][64][32];       // [kb][qrow][32 keys] (wave-private rows)
    __shared__ u16 SsB[2][64][32];

    const int t = threadIdx.x, w = t >> 6, lane = t & 63;
    const int quad = lane >> 4, m16 = lane & 15;
    const int p = blockIdx.x, h = blockIdx.y, b = blockIdx.z;
    const int tA = p, tB = 15 - p;
    const int srow = lane >> 2;
    const int s8x = ((lane & 3) ^ ((lane >> 3) & 3)) * 8;  // pre-swizzled src slot
    const int sx = (m16 >> 1) & 3;                          // read-side XOR factor
    const int qrow = w * 16 + m16;       // this lane's q-row (local to tile)

    const size_t qbase = (size_t)b * 1024 * 2048 + h * 64;
    const size_t kbase = qbase + 1024;
    const size_t vbase = ((size_t)b * 1024 + h * 64) * 1024;

    bf16x8 qfA[2], qfB[2];
#pragma unroll
    for (int kd = 0; kd < 2; ++kd) {
        qfA[kd] = *(const bf16x8*)(qkm + qbase +
                   (size_t)(tA * 64 + qrow) * 2048 + kd * 32 + quad * 8);
        qfB[kd] = *(const bf16x8*)(qkm + qbase +
                   (size_t)(tB * 64 + qrow) * 2048 + kd * 32 + quad * 8);
    }

    auto stage_tile = [&](int kt, int buf, int slot) {
#pragma unroll
        for (int cc = 0; cc < 2; ++cc) {
            const int c = w * 2 + cc;
            const int blk = c >> 2, rc = c & 3;
            gll16(qkm + kbase + (size_t)(kt * 64 + rc * 16 + srow) * 2048 + blk * 32 + s8x,
                  &ks[buf][slot][blk][rc * 16][0]);
            gll16(vT + vbase + (size_t)(rc * 16 + srow) * 1024 + kt * 64 + blk * 32 + s8x,
                  &vs[buf][slot][blk][rc * 16][0]);
        }
    };

    bf16x8 ones;
#pragma unroll
    for (int e = 0; e < 8; ++e) ones[e] = (short)0x3F80;

    f32x4 numA[4], numB[4], denA, denB;
    denA = denB = (f32x4){0.f, 0.f, 0.f, 0.f};
#pragma unroll
    for (int j = 0; j < 4; ++j) numA[j] = numB[j] = (f32x4){0.f, 0.f, 0.f, 0.f};

    auto compute = [&](int buf, int slot, int kt) {
        const bool doA = (kt <= tA);
        f32x4 sA[4], sB[4];
#pragma unroll
        for (int jk = 0; jk < 4; ++jk)
            sA[jk] = sB[jk] = (f32x4){0.f, 0.f, 0.f, 0.f};
        __builtin_amdgcn_s_setprio(1);
#pragma unroll
        for (int kd = 0; kd < 2; ++kd)
#pragma unroll
            for (int jk = 0; jk < 4; ++jk) {
                bf16x8 af = *(const bf16x8*)
                    &ks[buf][slot][kd][jk * 16 + m16][(quad ^ sx) * 8];
                sB[jk] = MFMA16(af, qfB[kd], sB[jk]);
                if (doA) sA[jk] = MFMA16(af, qfA[kd], sA[jk]);
            }
        __builtin_amdgcn_s_setprio(0);
#pragma unroll
        for (int jk = 0; jk < 4; ++jk) {
            const int kl = jk * 16 + quad * 4;
            // swizzled Ss slot for this uint2: logical 16B-slot = (jk&1)*2+(quad>>1)
            const int sidx = ((((jk & 1) * 2 + (quad >> 1)) ^ sx) << 3) +
                             ((quad & 1) << 2);
            float scB[4];
#pragma unroll
            for (int r = 0; r < 4; ++r) {
                const float u = fmaf(sB[jk][r], 0.125f, 1.0f);
                scB[r] = fmaf(u * 0.5f, u, 0.5f);
            }
            if (kt == tB) {
#pragma unroll
                for (int r = 0; r < 4; ++r)
                    if (kl + r > qrow) scB[r] = 0.f;
            }
            *(uint2*)&SsB[jk >> 1][qrow][sidx] =
                make_uint2(pkcvt(scB[0], scB[1]), pkcvt(scB[2], scB[3]));
            if (doA) {
                float scA[4];
#pragma unroll
                for (int r = 0; r < 4; ++r) {
                    const float u = fmaf(sA[jk][r], 0.125f, 1.0f);
                    scA[r] = fmaf(u * 0.5f, u, 0.5f);
                }
                if (kt == tA) {
#pragma unroll
                    for (int r = 0; r < 4; ++r)
                        if (kl + r > qrow) scA[r] = 0.f;
                }
                *(uint2*)&SsA[jk >> 1][qrow][sidx] =
                    make_uint2(pkcvt(scA[0], scA[1]), pkcvt(scA[2], scA[3]));
            }
        }
        __builtin_amdgcn_s_setprio(1);
#pragma unroll
        for (int kb = 0; kb < 2; ++kb) {
            bf16x8 vf[4];
#pragma unroll
            for (int j = 0; j < 4; ++j)
                vf[j] = *(const bf16x8*)
                    &vs[buf][slot][kb][j * 16 + m16][(quad ^ sx) * 8];
            bf16x8 sfB = *(const bf16x8*)&SsB[kb][qrow][(quad ^ sx) * 8];
#pragma unroll
            for (int j = 0; j < 4; ++j) numB[j] = MFMA16(sfB, vf[j], numB[j]);
            denB = MFMA16(sfB, ones, denB);
            if (doA) {
                bf16x8 sfA = *(const bf16x8*)&SsA[kb][qrow][(quad ^ sx) * 8];
#pragma unroll
                for (int j = 0; j < 4; ++j) numA[j] = MFMA16(sfA, vf[j], numA[j]);
                denA = MFMA16(sfA, ones, denA);
            }
        }
        __builtin_amdgcn_s_setprio(0);
    };

    stage_tile(0, 0, 0);
    stage_tile(1, 0, 1);

    const int ngroups = (tB + 2) >> 1;
    for (int g = 0; g < ngroups; ++g) {
        const int buf = g & 1;
        __syncthreads();
        const int kn = (g + 1) * 2;
        if (kn <= tB) {
            stage_tile(kn, buf ^ 1, 0);
            if (kn + 1 <= tB) stage_tile(kn + 1, buf ^ 1, 1);
        }
        const int kt0 = g * 2;
        compute(buf, 0, kt0);
        if (kt0 + 1 <= tB) compute(buf, 1, kt0 + 1);
    }

#pragma unroll
    for (int r = 0; r < 4; ++r) {
        const float invA = 1.0f / denA[r], invB = 1.0f / denB[r];
        const int rowoff = w * 16 + quad * 4 + r;
        const size_t tokA = (size_t)(b * 1024 + tA * 64 + rowoff);
        const size_t tokB = (size_t)(b * 1024 + tB * 64 + rowoff);
#pragma unroll
        for (int j = 0; j < 4; ++j) {
            o[tokA * 1024 + h * 64 + j * 16 + m16] = f2b(numA[j][r] * invA);
            o[tokB * 1024 + h * 64 + j * 16 + m16] = f2b(numB[j][r] * invB);
        }
    }
}

// ---------------------------------------------------------------- launch
extern "C" void kernel_launch(void* const* d_in, const int* in_sizes, int n_in,
                              void* d_out, int out_size, void* d_ws, size_t ws_size,
                              hipStream_t stream) {
    const float* x  = (const float*)d_in[0];
    const float* Wq = (const float*)d_in[1];
    const float* Wk = (const float*)d_in[2];
    const float* Wv = (const float*)d_in[3];
    const float* Wo = (const float*)d_in[4];
    float* out = (float*)d_out;

    const size_t MEL = 4096ull * 1024ull;        // 4M elements
    u16* xb   = (u16*)d_ws;                      // 4096 x 1024
    u16* Wqkv = xb + MEL;                        // 3072 x 1024 (Wq|Wk|Wv rows)
    u16* Wob  = Wqkv + 3ull * 1024 * 1024;       // 1024 x 1024
    u16* qk   = Wob + 1024ull * 1024;            // 4096 x 2048 (q|k)
    u16* vT   = qk + 2ull * MEL;                 // [b*1024+h*64+vd][1024 tokens]
    u16* o    = vT + MEL;                        // 4096 x 1024

    cast_all<<<4096, 256, 0, stream>>>(x, Wq, Wk, Wv, Wo, xb, Wqkv);

    dim3 gq(32, 24);   // 128^2, 768 blocks = 3/CU (R4 proven)
    gemm_bt<128, 128, 1, 1><<<gq, 256, 0, stream>>>(xb, Wqkv, qk, vT, 1024, 2048);

    // R13: R4 attn + LDS swizzle (pairing kept; grid 512 = 2/CU)
    dim3 ga(8, 16, 4); // pair index x heads x batch — uniform work per block
    based_attn<<<ga, 256, 0, stream>>>(qk, vT, o);

    dim3 go(32, 16);   // o-proj 128x64, 512 blocks = 2/CU (R4 proven)
    gemm_bt<128, 64, 0, 2><<<go, 256, 0, stream>>>(o, Wob, (void*)out, nullptr, 1024, 1024);
}